// Round 1
// baseline (2153.122 us; speedup 1.0000x reference)
//
#include <hip/hip_runtime.h>
#include <hip/hip_bf16.h>

typedef __attribute__((ext_vector_type(8))) short bf16x8;
typedef __attribute__((ext_vector_type(4))) float f32x4;

#define EPS 1e-5f

// ---------------------------------------------------------------------------
// K1: mu[b,j,o] = relu(fc_b[j,o] + sum_i style[b,j,i]*fc_w[j,o,i])
// grid (2, 19), block 256. Each thread: one o, all 8 b simultaneously.
// ---------------------------------------------------------------------------
__global__ __launch_bounds__(256) void k1_mu(const float* __restrict__ style,
                                             const float* __restrict__ fc_w,
                                             const float* __restrict__ fc_b,
                                             float* __restrict__ mu) {
    const int j = blockIdx.y;
    const int o = blockIdx.x * 256 + threadIdx.x;
    __shared__ float s_lds[8 * 512];
    for (int i = threadIdx.x; i < 8 * 512; i += 256) {
        int b = i >> 9, ii = i & 511;
        s_lds[i] = style[(b * 19 + j) * 512 + ii];
    }
    __syncthreads();
    float acc[8];
#pragma unroll
    for (int b = 0; b < 8; ++b) acc[b] = 0.f;
    const float* wrow = fc_w + ((size_t)j * 512 + o) * 512;
    for (int i = 0; i < 512; i += 4) {
        float4 w4 = *(const float4*)(wrow + i);
#pragma unroll
        for (int b = 0; b < 8; ++b) {
            acc[b] += s_lds[b * 512 + i]     * w4.x + s_lds[b * 512 + i + 1] * w4.y
                    + s_lds[b * 512 + i + 2] * w4.z + s_lds[b * 512 + i + 3] * w4.w;
        }
    }
    const float bias = fc_b[j * 512 + o];
#pragma unroll
    for (int b = 0; b < 8; ++b) {
        float v = acc[b] + bias;
        mu[((size_t)b * 19 + j) * 512 + o] = v > 0.f ? v : 0.f;
    }
}

// ---------------------------------------------------------------------------
// K2: G[b,j,tap,co] = sum_s mu[b,j,s] * W[co,s,tap]   (avg-branch fold tables)
// grid (256 co, 8 b, 2 gamma/beta), block 256.
// ---------------------------------------------------------------------------
__global__ __launch_bounds__(256) void k2_tables(const float* __restrict__ mu,
                                                 const float* __restrict__ wg,
                                                 const float* __restrict__ wb,
                                                 float* __restrict__ Gg,
                                                 float* __restrict__ Gb) {
    const int co = blockIdx.x, b = blockIdx.y, g = blockIdx.z;
    const float* wsrc = g ? wb : wg;
    float* dst = g ? Gb : Gg;
    __shared__ float w_lds[4608];        // W[co, s(512), tap(9)]
    __shared__ float mu_lds[19 * 512];
    for (int i = threadIdx.x; i < 4608; i += 256) w_lds[i] = wsrc[(size_t)co * 4608 + i];
    for (int i = threadIdx.x; i < 19 * 512; i += 256) mu_lds[i] = mu[(size_t)b * 19 * 512 + i];
    __syncthreads();
    for (int t = threadIdx.x; t < 171; t += 256) {   // 19 j * 9 tap
        int j = t / 9, k = t - j * 9;
        float acc = 0.f;
        const float* mrow = &mu_lds[j * 512];
        for (int s = 0; s < 512; ++s) acc += mrow[s] * w_lds[s * 9 + k];
        dst[(((size_t)b * 19 + j) * 9 + k) * 256 + co] = acc;
    }
}

// ---------------------------------------------------------------------------
// K3: per-(b,c) mean / rstd of x + noise_inj over HxW (biased var)
// grid (256 c, 8 b), block 256.
// ---------------------------------------------------------------------------
__global__ __launch_bounds__(256) void k3_stats(const float* __restrict__ x,
                                                const float* __restrict__ noise,
                                                const float* __restrict__ nv,
                                                float* __restrict__ mean,
                                                float* __restrict__ rstd) {
    const int c = blockIdx.x, b = blockIdx.y;
    const float* xp = x + ((size_t)(b * 256 + c)) * 16384;
    const float* np = noise + (size_t)b * 16384;
    const float nvc = nv[c];
    float s = 0.f, s2 = 0.f;
    for (int i = threadIdx.x; i < 16384; i += 256) {
        int h = i >> 7, w = i & 127;
        float v = xp[i] + np[w * 128 + h] * nvc;    // noise is (B,W,H,1)
        s += v; s2 += v * v;
    }
#pragma unroll
    for (int o = 32; o > 0; o >>= 1) { s += __shfl_down(s, o); s2 += __shfl_down(s2, o); }
    __shared__ float red[8];
    const int wave = threadIdx.x >> 6, lane = threadIdx.x & 63;
    if (lane == 0) { red[wave] = s; red[4 + wave] = s2; }
    __syncthreads();
    if (threadIdx.x == 0) {
        float S  = red[0] + red[1] + red[2] + red[3];
        float S2 = red[4] + red[5] + red[6] + red[7];
        float m = S * (1.f / 16384.f);
        float var = S2 * (1.f / 16384.f) - m * m;
        mean[b * 256 + c] = m;
        rstd[b * 256 + c] = rsqrtf(var + EPS);
    }
}

// ---------------------------------------------------------------------------
// K4: actv[b,h,w,nh] (NHWC bf16) = relu(ssb[nh] + sum_taps ssw[nh, seg(p+tap), tap])
// grid (128 h, 8 b), block 256.
// ---------------------------------------------------------------------------
__global__ __launch_bounds__(256) void k4_actv(const int* __restrict__ seg,
                                               const float* __restrict__ spw,
                                               const float* __restrict__ spb,
                                               __hip_bfloat16* __restrict__ actv) {
    const int h = blockIdx.x, b = blockIdx.y;
    __shared__ int lab[3][128];
    for (int i = threadIdx.x; i < 384; i += 256) {
        int dy = i >> 7, w = i & 127;
        int hh = h + dy - 1;
        lab[dy][w] = (hh >= 0 && hh < 128) ? seg[((size_t)b * 128 + hh) * 128 + w] : -1;
    }
    __syncthreads();
    const int nh = threadIdx.x & 127;
    const int w0 = threadIdx.x >> 7;
    const float bias = spb[nh];
    const float* wrow = spw + nh * 19 * 9;
    for (int wi = 0; wi < 64; ++wi) {
        int w = wi * 2 + w0;
        float acc = bias;
#pragma unroll
        for (int dy = 0; dy < 3; ++dy) {
#pragma unroll
            for (int dx = 0; dx < 3; ++dx) {
                int ww = w + dx - 1;
                if (ww >= 0 && ww < 128) {
                    int j = lab[dy][ww];
                    if (j >= 0) acc += wrow[j * 9 + dy * 3 + dx];
                }
            }
        }
        float r = acc > 0.f ? acc : 0.f;
        actv[(((size_t)(b * 128 + h)) * 128 + w) * 128 + nh] = __float2bfloat16(r);
    }
}

// ---------------------------------------------------------------------------
// K4b: weight transpose for the spade implicit GEMM:
// Wt[tap][n'][nh] bf16 with n' = 2*co + (0=gamma,1=beta)
// ---------------------------------------------------------------------------
__global__ __launch_bounds__(256) void k4b_wt(const float* __restrict__ wg,
                                              const float* __restrict__ wb,
                                              __hip_bfloat16* __restrict__ Wt) {
    int idx = blockIdx.x * 256 + threadIdx.x;  // < 9*512*128 = 589824
    int nh = idx & 127;
    int np = (idx >> 7) & 511;
    int tap = idx >> 16;
    int co = np >> 1, g = np & 1;
    const float* src = g ? wb : wg;
    Wt[idx] = __float2bfloat16(src[((size_t)co * 128 + nh) * 9 + tap]);
}

// ---------------------------------------------------------------------------
// K5: implicit-GEMM spade convs (M=128 px row, N=64 interleaved g/b chans,
// K=9 taps x 128 nh) + fused epilogue: avg-branch table gather, blend,
// instance-norm, final write. grid (8 nblk, 128 h, 8 b), block 256 (4 waves).
// ---------------------------------------------------------------------------
#define AST 136   // padded nh-stride in LDS (128 + 8 breaks bank conflicts)

__global__ __launch_bounds__(256) void k5_main(
    const __hip_bfloat16* __restrict__ actv,
    const __hip_bfloat16* __restrict__ Wt,
    const float* __restrict__ Gg, const float* __restrict__ Gb,
    const float* __restrict__ meanp, const float* __restrict__ rstdp,
    const float* __restrict__ x, const int* __restrict__ seg,
    const float* __restrict__ noise, const float* __restrict__ nv,
    const float* __restrict__ cgb, const float* __restrict__ cbb,
    const float* __restrict__ sgb, const float* __restrict__ sbb,
    const float* __restrict__ bgam, const float* __restrict__ bbet,
    float* __restrict__ out)
{
    const int nblk = blockIdx.x;      // 0..7 -> co range [nblk*32, nblk*32+32)
    const int h    = blockIdx.y;
    const int b    = blockIdx.z;
    const int n0   = nblk * 64;

    __shared__ __align__(16) char smem[130 * AST * 2 + 64 * AST * 2];
    __hip_bfloat16* Albs = (__hip_bfloat16*)smem;                 // 130 x AST bf16
    __hip_bfloat16* Blds = (__hip_bfloat16*)(smem + 130 * AST * 2); // 64 x AST bf16
    float* Clds = (float*)smem;                                    // 128 x 68 f32 (aliases A)

    const int tid  = threadIdx.x;
    const int wave = tid >> 6;
    const int lane = tid & 63;
    const int lm = lane & 15;
    const int lq = lane >> 4;

    f32x4 acc[2][4];
#pragma unroll
    for (int mt = 0; mt < 2; ++mt)
#pragma unroll
        for (int nt = 0; nt < 4; ++nt)
            acc[mt][nt] = (f32x4){0.f, 0.f, 0.f, 0.f};

    // zero halo columns: col 0 (w=-1) and col 129 (w=128)
    {
        __hip_bfloat16 z = __float2bfloat16(0.f);
        if (tid < 128) Albs[tid] = z;
        else           Albs[129 * AST + (tid - 128)] = z;
    }

    for (int dy = 0; dy < 3; ++dy) {
        const int hh = h + dy - 1;
        if (hh < 0 || hh >= 128) continue;   // SAME padding row: contributes 0
        __syncthreads();                      // protect previous reads of Albs
        const uint4* asrc = (const uint4*)(actv + (((size_t)(b * 128 + hh)) * 128) * 128);
        for (int ci = tid; ci < 2048; ci += 256) {      // 128 px * 16 chunks of 16B
            int px = ci >> 4, nh16 = ci & 15;
            *(uint4*)(Albs + (px + 1) * AST + nh16 * 8) = asrc[ci];
        }
        __syncthreads();
        for (int dx = 0; dx < 3; ++dx) {
            const int tap = dy * 3 + dx;
            __syncthreads();                  // protect previous tap's Blds reads
            const uint4* bsrc = (const uint4*)(Wt + ((size_t)tap * 512 + n0) * 128);
            for (int ci = tid; ci < 1024; ci += 256) {  // 64 n * 16 chunks
                int n = ci >> 4, nh16 = ci & 15;
                *(uint4*)(Blds + n * AST + nh16 * 8) = bsrc[ci];
            }
            __syncthreads();
            const int arow0 = wave * 32 + lm + dx;      // lds col = px + dx
#pragma unroll
            for (int ks = 0; ks < 4; ++ks) {
                const int kb = ks * 32 + lq * 8;
                bf16x8 a0 = *(const bf16x8*)(Albs + (arow0)      * AST + kb);
                bf16x8 a1 = *(const bf16x8*)(Albs + (arow0 + 16) * AST + kb);
                bf16x8 b0 = *(const bf16x8*)(Blds + (lm)      * AST + kb);
                bf16x8 b1 = *(const bf16x8*)(Blds + (16 + lm) * AST + kb);
                bf16x8 b2 = *(const bf16x8*)(Blds + (32 + lm) * AST + kb);
                bf16x8 b3 = *(const bf16x8*)(Blds + (48 + lm) * AST + kb);
                acc[0][0] = __builtin_amdgcn_mfma_f32_16x16x32_bf16(a0, b0, acc[0][0], 0, 0, 0);
                acc[0][1] = __builtin_amdgcn_mfma_f32_16x16x32_bf16(a0, b1, acc[0][1], 0, 0, 0);
                acc[0][2] = __builtin_amdgcn_mfma_f32_16x16x32_bf16(a0, b2, acc[0][2], 0, 0, 0);
                acc[0][3] = __builtin_amdgcn_mfma_f32_16x16x32_bf16(a0, b3, acc[0][3], 0, 0, 0);
                acc[1][0] = __builtin_amdgcn_mfma_f32_16x16x32_bf16(a1, b0, acc[1][0], 0, 0, 0);
                acc[1][1] = __builtin_amdgcn_mfma_f32_16x16x32_bf16(a1, b1, acc[1][1], 0, 0, 0);
                acc[1][2] = __builtin_amdgcn_mfma_f32_16x16x32_bf16(a1, b2, acc[1][2], 0, 0, 0);
                acc[1][3] = __builtin_amdgcn_mfma_f32_16x16x32_bf16(a1, b3, acc[1][3], 0, 0, 0);
            }
        }
    }

    // ---- epilogue: acc -> LDS (C/D layout: col=lane&15, row=(lane>>4)*4+reg) ----
    __syncthreads();   // everyone done reading Albs before aliasing as Clds
#pragma unroll
    for (int mt = 0; mt < 2; ++mt) {
        const int row = wave * 32 + mt * 16 + lq * 4;
#pragma unroll
        for (int nt = 0; nt < 4; ++nt) {
            const int col = nt * 16 + lm;
#pragma unroll
            for (int r = 0; r < 4; ++r)
                Clds[(row + r) * 68 + col] = acc[mt][nt][r];
        }
    }
    __syncthreads();

    // ---- fused final: blend + instance norm + write ----
    const int px = tid & 127;
    const int half = tid >> 7;
    int labs[9];
#pragma unroll
    for (int dy = 0; dy < 3; ++dy)
#pragma unroll
        for (int dx = 0; dx < 3; ++dx) {
            int hh2 = h + dy - 1, ww2 = px + dx - 1;
            labs[dy * 3 + dx] = (hh2 >= 0 && hh2 < 128 && ww2 >= 0 && ww2 < 128)
                                ? seg[((size_t)b * 128 + hh2) * 128 + ww2] : -1;
        }
    const float nval = noise[(size_t)b * 16384 + px * 128 + h];
    const float ga = 1.f / (1.f + expf(-bgam[0]));
    const float ba = 1.f / (1.f + expf(-bbet[0]));
    const size_t GgB = (size_t)b * 19 * 9 * 256;
#pragma unroll 4
    for (int i = 0; i < 16; ++i) {
        const int cl = i * 2 + half;          // 0..31
        const int co = nblk * 32 + cl;
        float gsp = Clds[px * 68 + 2 * cl]     + sgb[co];
        float bsp = Clds[px * 68 + 2 * cl + 1] + sbb[co];
        float gav = cgb[co], bav = cbb[co];
#pragma unroll
        for (int k = 0; k < 9; ++k) {
            int j = labs[k];
            if (j >= 0) {
                size_t off = GgB + ((size_t)(j * 9 + k)) * 256 + co;
                gav += Gg[off];
                bav += Gb[off];
            }
        }
        const float gf = ga * gav + (1.f - ga) * gsp;
        const float bf = ba * bav + (1.f - ba) * bsp;
        const size_t xo = (((size_t)(b * 256 + co)) * 128 + h) * 128 + px;
        const float nrm = (x[xo] + nval * nv[co] - meanp[b * 256 + co]) * rstdp[b * 256 + co];
        out[xo] = nrm * (1.f + gf) + bf;
    }
}

// ---------------------------------------------------------------------------
extern "C" void kernel_launch(void* const* d_in, const int* in_sizes, int n_in,
                              void* d_out, int out_size, void* d_ws, size_t ws_size,
                              hipStream_t stream) {
    const float* x      = (const float*)d_in[0];
    const int*   seg    = (const int*)d_in[1];
    const float* style  = (const float*)d_in[2];
    const float* noise  = (const float*)d_in[3];
    const float* nv     = (const float*)d_in[4];
    const float* bgam   = (const float*)d_in[5];
    const float* bbet   = (const float*)d_in[6];
    const float* fc_w   = (const float*)d_in[7];
    const float* fc_b   = (const float*)d_in[8];
    const float* cgw    = (const float*)d_in[9];
    const float* cgbias = (const float*)d_in[10];
    const float* cbw    = (const float*)d_in[11];
    const float* cbbias = (const float*)d_in[12];
    const float* ssw    = (const float*)d_in[13];
    const float* ssb    = (const float*)d_in[14];
    const float* sgw    = (const float*)d_in[15];
    const float* sgbias = (const float*)d_in[16];
    const float* sbw    = (const float*)d_in[17];
    const float* sbbias = (const float*)d_in[18];
    float* out = (float*)d_out;

    char* ws = (char*)d_ws;
    float* mu   = (float*)ws;                   ws += (size_t)8 * 19 * 512 * 4;
    float* Gg   = (float*)ws;                   ws += (size_t)8 * 19 * 9 * 256 * 4;
    float* Gb   = (float*)ws;                   ws += (size_t)8 * 19 * 9 * 256 * 4;
    float* mean = (float*)ws;                   ws += 2048 * 4;
    float* rstd = (float*)ws;                   ws += 2048 * 4;
    __hip_bfloat16* Wt   = (__hip_bfloat16*)ws; ws += (size_t)9 * 512 * 128 * 2;
    __hip_bfloat16* actv = (__hip_bfloat16*)ws; // 8*128*128*128*2 = 33.5 MB

    k1_mu<<<dim3(2, 19), 256, 0, stream>>>(style, fc_w, fc_b, mu);
    k2_tables<<<dim3(256, 8, 2), 256, 0, stream>>>(mu, cgw, cbw, Gg, Gb);
    k3_stats<<<dim3(256, 8), 256, 0, stream>>>(x, noise, nv, mean, rstd);
    k4_actv<<<dim3(128, 8), 256, 0, stream>>>(seg, ssw, ssb, actv);
    k4b_wt<<<2304, 256, 0, stream>>>(sgw, sbw, Wt);
    k5_main<<<dim3(8, 128, 8), 256, 0, stream>>>(actv, Wt, Gg, Gb, mean, rstd,
                                                 x, seg, noise, nv,
                                                 cgbias, cbbias, sgbias, sbbias,
                                                 bgam, bbet, out);
}

// Round 2
// 1068.247 us; speedup vs baseline: 2.0156x; 2.0156x over previous
//
#include <hip/hip_runtime.h>
#include <hip/hip_bf16.h>

typedef __attribute__((ext_vector_type(8))) short bf16x8;
typedef __attribute__((ext_vector_type(4))) float f32x4;
typedef __attribute__((ext_vector_type(16))) float f32x16;

#define EPS 1e-5f

// ---------------------------------------------------------------------------
// K1: mu[b,j,o] = relu(fc_b[j,o] + sum_i style[b,j,i]*fc_w[j,o,i])
// grid (2 o-chunks, 19 j), block 256. fc_w staged in LDS coalesced.
// ---------------------------------------------------------------------------
__global__ __launch_bounds__(256) void k1_mu(const float* __restrict__ style,
                                             const float* __restrict__ fc_w,
                                             const float* __restrict__ fc_b,
                                             float* __restrict__ mu) {
    const int j = blockIdx.y;
    const int o0 = blockIdx.x * 256;
    __shared__ float s_sty[8 * 512];
    __shared__ float s_w[256 * 33];          // [o'][i] pad 33: conflict-free
    for (int i = threadIdx.x; i < 8 * 512; i += 256) {
        int b = i >> 9, ii = i & 511;
        s_sty[i] = style[(b * 19 + j) * 512 + ii];
    }
    float acc[8];
#pragma unroll
    for (int b = 0; b < 8; ++b) acc[b] = 0.f;
    const float* wbase = fc_w + ((size_t)j * 512 + o0) * 512;
    for (int ic = 0; ic < 16; ++ic) {
        __syncthreads();
        for (int idx = threadIdx.x; idx < 8192; idx += 256) {
            int op = idx >> 5, ii = idx & 31;
            s_w[op * 33 + ii] = wbase[(size_t)op * 512 + ic * 32 + ii];
        }
        __syncthreads();
#pragma unroll 8
        for (int ii = 0; ii < 32; ++ii) {
            float wv = s_w[threadIdx.x * 33 + ii];
            int ib = ic * 32 + ii;
#pragma unroll
            for (int b = 0; b < 8; ++b) acc[b] += s_sty[b * 512 + ib] * wv;
        }
    }
    const float bias = fc_b[j * 512 + o0 + threadIdx.x];
#pragma unroll
    for (int b = 0; b < 8; ++b) {
        float v = acc[b] + bias;
        mu[((size_t)b * 19 + j) * 512 + o0 + threadIdx.x] = v > 0.f ? v : 0.f;
    }
}

// ---------------------------------------------------------------------------
// K2: G[b,jk,co] = sum_s mu[b,j,s]*W[co,s,k] for both tables in one block.
// grid (256 co, 8 b), block 256. mu padded 513 -> bank-conflict-free.
// ---------------------------------------------------------------------------
__global__ __launch_bounds__(256) void k2_tables(const float* __restrict__ mu,
                                                 const float* __restrict__ wg,
                                                 const float* __restrict__ wb,
                                                 float* __restrict__ Gg,
                                                 float* __restrict__ Gb) {
    const int co = blockIdx.x, b = blockIdx.y;
    __shared__ float w_lds[2][4608];          // [g][s*9+k]
    __shared__ float mu_lds[19 * 513];
    for (int i = threadIdx.x; i < 4608; i += 256) {
        w_lds[0][i] = wg[(size_t)co * 4608 + i];
        w_lds[1][i] = wb[(size_t)co * 4608 + i];
    }
    for (int i = threadIdx.x; i < 19 * 512; i += 256) {
        int jj = i >> 9, s = i & 511;
        mu_lds[jj * 513 + s] = mu[(size_t)b * 19 * 512 + i];
    }
    __syncthreads();
    for (int t = threadIdx.x; t < 342; t += 256) {
        int g = t >= 171 ? 1 : 0;
        int jk = t - g * 171;
        int jj = jk / 9, k = jk - jj * 9;
        const float* w = w_lds[g];
        const float* m = &mu_lds[jj * 513];
        float acc = 0.f;
        for (int s = 0; s < 512; ++s) acc += m[s] * w[s * 9 + k];
        float* dst = g ? Gb : Gg;
        dst[((size_t)b * 171 + jk) * 256 + co] = acc;
    }
}

// ---------------------------------------------------------------------------
// K3: per-(b,c) mean / rstd of x + noise_inj over HxW (biased var)
// ---------------------------------------------------------------------------
__global__ __launch_bounds__(256) void k3_stats(const float* __restrict__ x,
                                                const float* __restrict__ noise,
                                                const float* __restrict__ nv,
                                                float* __restrict__ mean,
                                                float* __restrict__ rstd) {
    const int c = blockIdx.x, b = blockIdx.y;
    const float* xp = x + ((size_t)(b * 256 + c)) * 16384;
    const float* np = noise + (size_t)b * 16384;
    const float nvc = nv[c];
    float s = 0.f, s2 = 0.f;
    for (int i = threadIdx.x; i < 16384; i += 256) {
        int h = i >> 7, w = i & 127;
        float v = xp[i] + np[w * 128 + h] * nvc;    // noise is (B,W,H,1)
        s += v; s2 += v * v;
    }
#pragma unroll
    for (int o = 32; o > 0; o >>= 1) { s += __shfl_down(s, o); s2 += __shfl_down(s2, o); }
    __shared__ float red[8];
    const int wave = threadIdx.x >> 6, lane = threadIdx.x & 63;
    if (lane == 0) { red[wave] = s; red[4 + wave] = s2; }
    __syncthreads();
    if (threadIdx.x == 0) {
        float S  = red[0] + red[1] + red[2] + red[3];
        float S2 = red[4] + red[5] + red[6] + red[7];
        float m = S * (1.f / 16384.f);
        float var = S2 * (1.f / 16384.f) - m * m;
        mean[b * 256 + c] = m;
        rstd[b * 256 + c] = rsqrtf(var + EPS);
    }
}

// ---------------------------------------------------------------------------
// K4: actv[b,h,w,nh] NHWC bf16 = relu(ssb[nh] + sum_taps ssw[nh, j(p+tap), tap])
// weights transposed into LDS [jk][nh] bf16 pad 130 -> conflict-free reads.
// grid (128 h, 8 b), block 256.
// ---------------------------------------------------------------------------
__global__ __launch_bounds__(256) void k4_actv(const int* __restrict__ seg,
                                               const float* __restrict__ spw,
                                               const float* __restrict__ spb,
                                               __hip_bfloat16* __restrict__ actv) {
    const int h = blockIdx.x, b = blockIdx.y;
    __shared__ __hip_bfloat16 wlds[171 * 130];
    __shared__ int lab[3][128];
    for (int i = threadIdx.x; i < 21888; i += 256) {   // 128 nh * 171 jk
        int nh = i / 171, jk = i - nh * 171;
        wlds[jk * 130 + nh] = __float2bfloat16(spw[i]);
    }
    for (int i = threadIdx.x; i < 384; i += 256) {
        int dy = i >> 7, w = i & 127;
        int hh = h + dy - 1;
        lab[dy][w] = (hh >= 0 && hh < 128) ? seg[((size_t)b * 128 + hh) * 128 + w] : -1;
    }
    __syncthreads();
    const int nh = threadIdx.x & 127;
    const int ws = threadIdx.x >> 7;
    const float bias = spb[nh];
    for (int wi = 0; wi < 64; ++wi) {
        int w = wi * 2 + ws;
        float acc = bias;
#pragma unroll
        for (int dy = 0; dy < 3; ++dy)
#pragma unroll
            for (int dx = 0; dx < 3; ++dx) {
                int ww = w + dx - 1;
                if (ww >= 0 && ww < 128) {
                    int j = lab[dy][ww];
                    if (j >= 0)
                        acc += __bfloat162float(wlds[(j * 9 + dy * 3 + dx) * 130 + nh]);
                }
            }
        float r = acc > 0.f ? acc : 0.f;
        actv[(((size_t)(b * 128 + h)) * 128 + w) * 128 + nh] = __float2bfloat16(r);
    }
}

// ---------------------------------------------------------------------------
// K4b: Wt[tap][n=2co+g][nh] bf16  (spade GEMM weight layout)
// ---------------------------------------------------------------------------
__global__ __launch_bounds__(256) void k4b_wt(const float* __restrict__ wg,
                                              const float* __restrict__ wb,
                                              __hip_bfloat16* __restrict__ Wt) {
    int idx = blockIdx.x * 256 + threadIdx.x;  // < 9*512*128
    int nh = idx & 127;
    int np = (idx >> 7) & 511;
    int tap = idx >> 16;
    int co = np >> 1, g = np & 1;
    const float* src = g ? wb : wg;
    Wt[idx] = __float2bfloat16(src[((size_t)co * 128 + nh) * 9 + tap]);
}

// ---------------------------------------------------------------------------
// K5a: pure implicit-GEMM, spade[b][n=2co+g][h][w] bf16.
// M=128 (one row), N=128, K=1152 (9 taps x 128 nh). 32x32x16 bf16 MFMA,
// wave tile 64x64 (2x2 of 32x32). A stride 272B, B stride 144B: both
// = 16 mod 32 bytes -> conflict-free column b128 reads. B double-buffered.
// grid (4 nblk, 128 h, 8 b), block 256.
// ---------------------------------------------------------------------------
#define ASTR 136   // bf16 elems per A row (130 rows), 272B: conflict-free
#define BSTR 72    // bf16 elems per B row (64 used), 144B: conflict-free

__global__ __launch_bounds__(256, 2) void k5a_gemm(
    const __hip_bfloat16* __restrict__ actv,
    const __hip_bfloat16* __restrict__ Wt,
    __hip_bfloat16* __restrict__ spade)
{
    const int nblk = blockIdx.x;
    const int h = blockIdx.y, b = blockIdx.z;
    const int n0 = nblk * 128;

    __shared__ __align__(16) char smem[130 * ASTR * 2 + 2 * 128 * BSTR * 2];
    __hip_bfloat16* A  = (__hip_bfloat16*)smem;                       // [130][ASTR]
    __hip_bfloat16* B0 = (__hip_bfloat16*)(smem + 130 * ASTR * 2);
    __hip_bfloat16* B1 = B0 + 128 * BSTR;
    __hip_bfloat16* C  = (__hip_bfloat16*)smem;                       // [128][ASTR] alias A

    const int tid = threadIdx.x;
    const int wave = tid >> 6, lane = tid & 63;
    const int wm = wave >> 1, wn = wave & 1;
    const int l31 = lane & 31, lq = lane >> 5;

    f32x16 acc[2][2];
#pragma unroll
    for (int mt = 0; mt < 2; ++mt)
#pragma unroll
        for (int nt = 0; nt < 2; ++nt)
#pragma unroll
            for (int r = 0; r < 16; ++r) acc[mt][nt][r] = 0.f;

    // zero halo px columns 0 and 129 once (never overwritten)
    {
        __hip_bfloat16 z = __float2bfloat16(0.f);
        if (tid < 128) A[tid] = z;
        else           A[129 * ASTR + (tid - 128)] = z;
    }

    auto stageA = [&](int dy) {
        int hh = h + dy - 1;
        if (hh < 0 || hh >= 128) {
            uint4 z = {0u, 0u, 0u, 0u};
            int ci = tid;
#pragma unroll
            for (int r = 0; r < 8; ++r, ci += 256) {
                int px = ci >> 4, c = ci & 15;
                *(uint4*)(A + (px + 1) * ASTR + c * 8) = z;
            }
        } else {
            const __hip_bfloat16* src = actv + (((size_t)(b * 128 + hh)) * 128) * 128;
            int ci = tid;
#pragma unroll
            for (int r = 0; r < 8; ++r, ci += 256) {
                int px = ci >> 4, c = ci & 15;
                uint4 v = *(const uint4*)(src + (size_t)px * 128 + c * 8);
                *(uint4*)(A + (px + 1) * ASTR + c * 8) = v;
            }
        }
    };
    auto stageB = [&](int s) {   // stage segment s's B chunk into buf s&1
        int dy = s / 6, rem = s - dy * 6, dx = rem >> 1, kc = rem & 1;
        int tap = dy * 3 + dx;
        __hip_bfloat16* Bd = (s & 1) ? B1 : B0;
        const __hip_bfloat16* src = Wt + ((size_t)tap * 512 + n0) * 128 + kc * 64;
        int ci = tid;
#pragma unroll
        for (int r = 0; r < 4; ++r, ci += 256) {
            int n = ci >> 3, c = ci & 7;
            uint4 v = *(const uint4*)(src + (size_t)n * 128 + c * 8);
            *(uint4*)(Bd + n * BSTR + c * 8) = v;
        }
    };

    stageB(0);
    for (int s = 0; s < 18; ++s) {
        int dy = s / 6, rem = s - dy * 6;
        int dx = rem >> 1, kc = rem & 1;
        if (rem == 0) { if (s) __syncthreads(); stageA(dy); }
        __syncthreads();
        if (s < 17) stageB(s + 1);   // loads overlap compute; visible at next barrier
        const __hip_bfloat16* Bs = (s & 1) ? B1 : B0;
        const __hip_bfloat16* Abase = A + (wm * 64 + l31 + dx) * ASTR + kc * 64 + lq * 8;
        const __hip_bfloat16* Bbase = Bs + (wn * 64 + l31) * BSTR + lq * 8;
#pragma unroll
        for (int ks = 0; ks < 4; ++ks) {
            bf16x8 a0 = *(const bf16x8*)(Abase + ks * 16);
            bf16x8 a1 = *(const bf16x8*)(Abase + 32 * ASTR + ks * 16);
            bf16x8 b0 = *(const bf16x8*)(Bbase + ks * 16);
            bf16x8 b1 = *(const bf16x8*)(Bbase + 32 * BSTR + ks * 16);
            acc[0][0] = __builtin_amdgcn_mfma_f32_32x32x16_bf16(a0, b0, acc[0][0], 0, 0, 0);
            acc[0][1] = __builtin_amdgcn_mfma_f32_32x32x16_bf16(a0, b1, acc[0][1], 0, 0, 0);
            acc[1][0] = __builtin_amdgcn_mfma_f32_32x32x16_bf16(a1, b0, acc[1][0], 0, 0, 0);
            acc[1][1] = __builtin_amdgcn_mfma_f32_32x32x16_bf16(a1, b1, acc[1][1], 0, 0, 0);
        }
    }

    __syncthreads();
    // acc -> C LDS as bf16 [n][px]: C/D layout col=lane&31(=n), row=(r&3)+8*(r>>2)+4*lq(=px)
#pragma unroll
    for (int mt = 0; mt < 2; ++mt)
#pragma unroll
        for (int nt = 0; nt < 2; ++nt) {
            int ncol = wn * 64 + nt * 32 + l31;
#pragma unroll
            for (int r = 0; r < 16; ++r) {
                int row = wm * 64 + mt * 32 + (r & 3) + 8 * (r >> 2) + 4 * lq;
                C[ncol * ASTR + row] = __float2bfloat16(acc[mt][nt][r]);
            }
        }
    __syncthreads();
    {
        int ci = tid;
#pragma unroll
        for (int r = 0; r < 8; ++r, ci += 256) {
            int n = ci >> 4, c = ci & 15;
            uint4 v = *(const uint4*)(C + n * ASTR + c * 8);
            *(uint4*)(spade + (((size_t)(b * 512 + n0 + n)) * 128 + h) * 128 + c * 8) = v;
        }
    }
}

// ---------------------------------------------------------------------------
// K5b: fused epilogue: avg-branch LDS-table gather + blend + noise +
// instance-norm + write. grid (8 co-chunk, 128 h, 8 b), block 256.
// ---------------------------------------------------------------------------
__global__ __launch_bounds__(256) void k5b_epi(
    const __hip_bfloat16* __restrict__ spade,
    const float* __restrict__ Gg, const float* __restrict__ Gb,
    const float* __restrict__ meanp, const float* __restrict__ rstdp,
    const float* __restrict__ x, const int* __restrict__ seg,
    const float* __restrict__ noise, const float* __restrict__ nv,
    const float* __restrict__ cgb, const float* __restrict__ cbb,
    const float* __restrict__ sgb, const float* __restrict__ sbb,
    const float* __restrict__ bgam, const float* __restrict__ bbet,
    float* __restrict__ out)
{
    const int cc = blockIdx.x;            // co chunk of 32
    const int h = blockIdx.y, b = blockIdx.z;
    const int co0 = cc * 32;
    __shared__ float Gl[2][171 * 33];     // pad 33: jk-gather conflict-free
    for (int i = threadIdx.x; i < 171 * 32; i += 256) {
        int jk = i >> 5, c = i & 31;
        size_t off = ((size_t)b * 171 + jk) * 256 + co0 + c;
        Gl[0][jk * 33 + c] = Gg[off];
        Gl[1][jk * 33 + c] = Gb[off];
    }
    __syncthreads();
    const int px = threadIdx.x & 127, half = threadIdx.x >> 7;
    int labs[9];
#pragma unroll
    for (int dy = 0; dy < 3; ++dy)
#pragma unroll
        for (int dx = 0; dx < 3; ++dx) {
            int hh = h + dy - 1, ww = px + dx - 1;
            labs[dy * 3 + dx] = (hh >= 0 && hh < 128 && ww >= 0 && ww < 128)
                                ? seg[((size_t)b * 128 + hh) * 128 + ww] : -1;
        }
    const float nval = noise[(size_t)b * 16384 + px * 128 + h];
    const float ga = 1.f / (1.f + expf(-bgam[0]));
    const float ba = 1.f / (1.f + expf(-bbet[0]));
#pragma unroll 2
    for (int i = 0; i < 16; ++i) {
        const int cl = i * 2 + half;
        const int co = co0 + cl;
        float gav = cgb[co], bav = cbb[co];
#pragma unroll
        for (int k = 0; k < 9; ++k) {
            int j = labs[k];
            if (j >= 0) {
                int o = (j * 9 + k) * 33 + cl;
                gav += Gl[0][o];
                bav += Gl[1][o];
            }
        }
        const size_t sp_off = (((size_t)(b * 512 + 2 * co)) * 128 + h) * 128 + px;
        float gsp = __bfloat162float(spade[sp_off]) + sgb[co];
        float bsp = __bfloat162float(spade[sp_off + 16384]) + sbb[co];
        const float gf = ga * gav + (1.f - ga) * gsp;
        const float bf = ba * bav + (1.f - ba) * bsp;
        const size_t xo = (((size_t)(b * 256 + co)) * 128 + h) * 128 + px;
        const float nrm = (x[xo] + nval * nv[co] - meanp[b * 256 + co]) * rstdp[b * 256 + co];
        out[xo] = nrm * (1.f + gf) + bf;
    }
}

// ---------------------------------------------------------------------------
extern "C" void kernel_launch(void* const* d_in, const int* in_sizes, int n_in,
                              void* d_out, int out_size, void* d_ws, size_t ws_size,
                              hipStream_t stream) {
    const float* x      = (const float*)d_in[0];
    const int*   seg    = (const int*)d_in[1];
    const float* style  = (const float*)d_in[2];
    const float* noise  = (const float*)d_in[3];
    const float* nv     = (const float*)d_in[4];
    const float* bgam   = (const float*)d_in[5];
    const float* bbet   = (const float*)d_in[6];
    const float* fc_w   = (const float*)d_in[7];
    const float* fc_b   = (const float*)d_in[8];
    const float* cgw    = (const float*)d_in[9];
    const float* cgbias = (const float*)d_in[10];
    const float* cbw    = (const float*)d_in[11];
    const float* cbbias = (const float*)d_in[12];
    const float* ssw    = (const float*)d_in[13];
    const float* ssb    = (const float*)d_in[14];
    const float* sgw    = (const float*)d_in[15];
    const float* sgbias = (const float*)d_in[16];
    const float* sbw    = (const float*)d_in[17];
    const float* sbbias = (const float*)d_in[18];
    float* out = (float*)d_out;

    char* ws = (char*)d_ws;
    float* mu   = (float*)ws;                   ws += (size_t)8 * 19 * 512 * 4;
    float* Gg   = (float*)ws;                   ws += (size_t)8 * 171 * 256 * 4;
    float* Gb   = (float*)ws;                   ws += (size_t)8 * 171 * 256 * 4;
    float* mean = (float*)ws;                   ws += 2048 * 4;
    float* rstd = (float*)ws;                   ws += 2048 * 4;
    __hip_bfloat16* Wt    = (__hip_bfloat16*)ws; ws += (size_t)9 * 512 * 128 * 2;
    __hip_bfloat16* actv  = (__hip_bfloat16*)ws; ws += (size_t)8 * 128 * 128 * 128 * 2;
    __hip_bfloat16* spade = (__hip_bfloat16*)ws; // 8*512*128*128*2 = 134 MB

    k1_mu<<<dim3(2, 19), 256, 0, stream>>>(style, fc_w, fc_b, mu);
    k2_tables<<<dim3(256, 8), 256, 0, stream>>>(mu, cgw, cbw, Gg, Gb);
    k3_stats<<<dim3(256, 8), 256, 0, stream>>>(x, noise, nv, mean, rstd);
    k4_actv<<<dim3(128, 8), 256, 0, stream>>>(seg, ssw, ssb, actv);
    k4b_wt<<<2304, 256, 0, stream>>>(sgw, sbw, Wt);
    k5a_gemm<<<dim3(4, 128, 8), 256, 0, stream>>>(actv, Wt, spade);
    k5b_epi<<<dim3(8, 128, 8), 256, 0, stream>>>(spade, Gg, Gb, mean, rstd,
                                                 x, seg, noise, nv,
                                                 cgbias, cbbias, sgbias, sbbias,
                                                 bgam, bbet, out);
}